// Round 1
// baseline (510.883 us; speedup 1.0000x reference)
//
#include <hip/hip_runtime.h>
#include <cstdint>
#include <cstddef>

#define B_   8
#define S_   1024
#define D_   768
#define H_   12
#define DK_  64
#define DFF_ 3072
#define M_   (B_*S_)   // 8192 token rows

typedef __attribute__((ext_vector_type(8))) short  short8;
typedef __attribute__((ext_vector_type(8))) __bf16 bf16x8;
typedef __attribute__((ext_vector_type(4))) float  f32x4;

__device__ __forceinline__ unsigned short f2bf(float f) {
    unsigned u = __builtin_bit_cast(unsigned, f);
    u += 0x7FFFu + ((u >> 16) & 1u);           // RNE
    return (unsigned short)(u >> 16);
}

__device__ __forceinline__ f32x4 mfma16(short8 a, short8 b, f32x4 c) {
    return __builtin_amdgcn_mfma_f32_16x16x32_bf16(
        __builtin_bit_cast(bf16x8, a), __builtin_bit_cast(bf16x8, b), c, 0, 0, 0);
}

__device__ __forceinline__ void gload16(const void* g, void* l) {
    auto gp = reinterpret_cast<const __attribute__((address_space(1))) unsigned*>(
        reinterpret_cast<uintptr_t>(g));
    auto lp = reinterpret_cast<__attribute__((address_space(3))) unsigned*>(
        reinterpret_cast<uintptr_t>(l));
    __builtin_amdgcn_global_load_lds(gp, lp, 16, 0, 0);
}

__device__ __forceinline__ float gelu_f(float v) {
    return 0.5f * v * (1.0f + erff(v * 0.70710678118654752f));
}

// ---- weight cast+transpose: W[K][N] fp32 -> Wt[N][K] bf16 ----
__global__ __launch_bounds__(256) void wtrans_kernel(
    const float* __restrict__ W, unsigned short* __restrict__ Wt, int K, int N)
{
    __shared__ float tile[32][33];
    int n0 = blockIdx.x * 32, k0 = blockIdx.y * 32;
    int tx = threadIdx.x, ty = threadIdx.y;   // 32 x 8
#pragma unroll
    for (int j = 0; j < 4; ++j)
        tile[ty + j*8][tx] = W[(size_t)(k0 + ty + j*8) * N + n0 + tx];
    __syncthreads();
#pragma unroll
    for (int j = 0; j < 4; ++j)
        Wt[(size_t)(n0 + ty + j*8) * K + k0 + tx] = f2bf(tile[tx][ty + j*8]);
}

// ---- LayerNorm fp32 -> bf16, one row (768) per block of 256 ----
__global__ __launch_bounds__(256) void ln_kernel(
    const float* __restrict__ x, const float* __restrict__ g,
    const float* __restrict__ b, unsigned short* __restrict__ out)
{
    int row = blockIdx.x, t = threadIdx.x;
    const float* xr = x + (size_t)row * D_;
    float v[3];
#pragma unroll
    for (int i = 0; i < 3; ++i) v[i] = xr[t + i*256];
    float s  = v[0] + v[1] + v[2];
    float ss = v[0]*v[0] + v[1]*v[1] + v[2]*v[2];
#pragma unroll
    for (int d = 1; d < 64; d <<= 1) { s += __shfl_xor(s, d); ss += __shfl_xor(ss, d); }
    __shared__ float red[8];
    int w = t >> 6, lane = t & 63;
    if (lane == 0) { red[w] = s; red[4 + w] = ss; }
    __syncthreads();
    s  = red[0] + red[1] + red[2] + red[3];
    ss = red[4] + red[5] + red[6] + red[7];
    float mu   = s * (1.0f / D_);
    float var  = ss * (1.0f / D_) - mu * mu;
    float rstd = rsqrtf(var + 1e-5f);
    unsigned short* orow = out + (size_t)row * D_;
#pragma unroll
    for (int i = 0; i < 3; ++i) {
        int c = t + i*256;
        orow[c] = f2bf((v[i] - mu) * rstd * g[c] + b[c]);
    }
}

// ---- m97-structure GEMM: C[M,N] = A[M,K](bf16) @ Wt[N,K]^T(bf16) ----
// EPI 0: store bf16 | EPI 1: +bias, gelu, store bf16 | EPI 2: (+bias)+resid, store fp32
template<int EPI>
__global__ __launch_bounds__(256) void gemm_kernel(
    const unsigned short* __restrict__ A, const unsigned short* __restrict__ Wt,
    const float* __restrict__ bias, const float* __restrict__ resid,
    void* __restrict__ outp, int N, int K)
{
    __shared__ unsigned short Al[128*32];
    __shared__ unsigned short Bl[128*32];
    const int nbn = N >> 7;
    const int bm = blockIdx.x / nbn, bn = blockIdx.x % nbn;
    const int t = threadIdx.x;
    const int lane = t & 63, w = t >> 6;
    const int wm = w >> 1, wn = w & 1;
    const int lr = lane & 15, lh = lane >> 4;
    const int rowS = t >> 2, colS = (t & 3) << 3;   // staging: 4 threads/row, 16B each
    const unsigned short* ag = A  + (size_t)(bm*128 + rowS) * K + colS;
    const unsigned short* bg = Wt + (size_t)(bn*128 + rowS) * K + colS;

    f32x4 acc[4][4] = {};

    for (int k0 = 0; k0 < K; k0 += 32) {
        gload16(ag + k0,                 &Al[t*8]);
        gload16(ag + (size_t)64*K + k0,  &Al[2048 + t*8]);
        gload16(bg + k0,                 &Bl[t*8]);
        gload16(bg + (size_t)64*K + k0,  &Bl[2048 + t*8]);
        __syncthreads();
        short8 af[4], bf[4];
#pragma unroll
        for (int i = 0; i < 4; ++i)
            af[i] = *reinterpret_cast<const short8*>(&Al[(wm*64 + i*16 + lr)*32 + lh*8]);
#pragma unroll
        for (int j = 0; j < 4; ++j)
            bf[j] = *reinterpret_cast<const short8*>(&Bl[(wn*64 + j*16 + lr)*32 + lh*8]);
#pragma unroll
        for (int i = 0; i < 4; ++i)
#pragma unroll
            for (int j = 0; j < 4; ++j)
                acc[i][j] = mfma16(af[i], bf[j], acc[i][j]);
        __syncthreads();
    }

#pragma unroll
    for (int i = 0; i < 4; ++i) {
#pragma unroll
        for (int r = 0; r < 4; ++r) {
            int row = bm*128 + wm*64 + i*16 + lh*4 + r;
#pragma unroll
            for (int j = 0; j < 4; ++j) {
                int col = bn*128 + wn*64 + j*16 + lr;
                float v = acc[i][j][r];
                if (EPI == 0) {
                    ((unsigned short*)outp)[(size_t)row*N + col] = f2bf(v);
                } else if (EPI == 1) {
                    v += bias[col];
                    v = gelu_f(v);
                    ((unsigned short*)outp)[(size_t)row*N + col] = f2bf(v);
                } else {
                    if (bias) v += bias[col];
                    v += resid[(size_t)row*N + col];
                    ((float*)outp)[(size_t)row*N + col] = v;
                }
            }
        }
    }
}

// ---- V transpose: qkv v-section [b,s,h,dk] -> vt[bh][dk][s] ----
__global__ __launch_bounds__(256) void vtrans_kernel(
    const unsigned short* __restrict__ qkv, unsigned short* __restrict__ vt)
{
    __shared__ unsigned short tl[64][65];
    int bid = blockIdx.x;
    int sblk = bid & 15, bh = bid >> 4;
    int b = bh / H_, h = bh % H_;
    int t = threadIdx.x, tx = t & 63, ty = t >> 6;
    int s0 = sblk * 64;
#pragma unroll
    for (int j = 0; j < 16; ++j) {
        int s = j*4 + ty;
        tl[s][tx] = qkv[(size_t)(b*S_ + s0 + s)*2304 + 1536 + h*64 + tx];
    }
    __syncthreads();
#pragma unroll
    for (int j = 0; j < 16; ++j) {
        int dk = j*4 + ty;
        vt[((size_t)bh*64 + dk)*S_ + s0 + tx] = tl[tx][dk];
    }
}

// ---- flash attention: per block (b,h,64 q-rows), 4 waves x 16 q-rows ----
__global__ __launch_bounds__(256) void attn_kernel(
    const unsigned short* __restrict__ qkv, const unsigned short* __restrict__ vt,
    unsigned short* __restrict__ out)
{
    __shared__ unsigned short p_lds[4][16*64];
    int bid = blockIdx.x;
    int qb = bid & 15, bh = bid >> 4;
    int b = bh / H_, h = bh % H_;
    int t = threadIdx.x, lane = t & 63, w = t >> 6;
    int lr = lane & 15, lh = lane >> 4;
    int qrow = qb*64 + w*16 + lr;

    const unsigned short* qp = qkv + (size_t)(b*S_ + qrow)*2304 + h*64;
    short8 aq0 = *reinterpret_cast<const short8*>(&qp[lh*8]);
    short8 aq1 = *reinterpret_cast<const short8*>(&qp[32 + lh*8]);

    float m_run[4], l_run[4];
    f32x4 o[4] = {};
#pragma unroll
    for (int r = 0; r < 4; ++r) { m_run[r] = -1e30f; l_run[r] = 0.0f; }

    const unsigned short* kbase = qkv + 768 + h*64;
    const unsigned short* vtb   = vt + (size_t)bh * 64 * S_;
    unsigned short* pw = &p_lds[w][0];

    for (int kb = 0; kb < 16; ++kb) {
        int ks = kb * 64;
        f32x4 s[4];
#pragma unroll
        for (int j = 0; j < 4; ++j) {
            const unsigned short* kp = kbase + (size_t)(b*S_ + ks + j*16 + lr)*2304;
            short8 bk0 = *reinterpret_cast<const short8*>(&kp[lh*8]);
            short8 bk1 = *reinterpret_cast<const short8*>(&kp[32 + lh*8]);
            f32x4 z = {0.f, 0.f, 0.f, 0.f};
            z = mfma16(aq0, bk0, z);
            z = mfma16(aq1, bk1, z);
            s[j] = z * 0.125f;   // DK^-0.5
        }
        float mt[4];
#pragma unroll
        for (int r = 0; r < 4; ++r)
            mt[r] = fmaxf(fmaxf(s[0][r], s[1][r]), fmaxf(s[2][r], s[3][r]));
#pragma unroll
        for (int d = 1; d < 16; d <<= 1)
#pragma unroll
            for (int r = 0; r < 4; ++r) mt[r] = fmaxf(mt[r], __shfl_xor(mt[r], d));
        float alpha[4], rs[4];
#pragma unroll
        for (int r = 0; r < 4; ++r) {
            float mn = fmaxf(m_run[r], mt[r]);
            alpha[r] = __expf(m_run[r] - mn);
            m_run[r] = mn;
            rs[r] = 0.f;
        }
#pragma unroll
        for (int j = 0; j < 4; ++j)
#pragma unroll
            for (int r = 0; r < 4; ++r) {
                float p = __expf(s[j][r] - m_run[r]);
                s[j][r] = p;
                rs[r] += p;
            }
#pragma unroll
        for (int d = 1; d < 16; d <<= 1)
#pragma unroll
            for (int r = 0; r < 4; ++r) rs[r] += __shfl_xor(rs[r], d);
#pragma unroll
        for (int r = 0; r < 4; ++r) l_run[r] = l_run[r]*alpha[r] + rs[r];
#pragma unroll
        for (int j = 0; j < 4; ++j)
#pragma unroll
            for (int r = 0; r < 4; ++r) o[j][r] *= alpha[r];
        // P (D-layout) -> LDS with XOR swizzle, then read back as A-frags
#pragma unroll
        for (int j = 0; j < 4; ++j)
#pragma unroll
            for (int r = 0; r < 4; ++r) {
                int prow = lh*4 + r;
                int pcol = (j*16 + lr) ^ ((prow & 7) << 3);
                pw[prow*64 + pcol] = f2bf(s[j][r]);
            }
        short8 pa0 = *reinterpret_cast<const short8*>(&pw[lr*64 + ((lh*8)      ^ ((lr & 7) << 3))]);
        short8 pa1 = *reinterpret_cast<const short8*>(&pw[lr*64 + ((32 + lh*8) ^ ((lr & 7) << 3))]);
#pragma unroll
        for (int j = 0; j < 4; ++j) {
            const unsigned short* vp = vtb + (size_t)(j*16 + lr)*S_ + ks;
            short8 bv0 = *reinterpret_cast<const short8*>(&vp[lh*8]);
            short8 bv1 = *reinterpret_cast<const short8*>(&vp[32 + lh*8]);
            o[j] = mfma16(pa0, bv0, o[j]);
            o[j] = mfma16(pa1, bv1, o[j]);
        }
    }
#pragma unroll
    for (int j = 0; j < 4; ++j)
#pragma unroll
        for (int r = 0; r < 4; ++r) {
            float v = o[j][r] / l_run[r];
            int row = qb*64 + w*16 + lh*4 + r;
            int col = h*64 + j*16 + lr;
            out[(size_t)(b*S_ + row)*D_ + col] = f2bf(v);
        }
}

extern "C" void kernel_launch(void* const* d_in, const int* in_sizes, int n_in,
                              void* d_out, int out_size, void* d_ws, size_t ws_size,
                              hipStream_t stream)
{
    (void)in_sizes; (void)n_in; (void)out_size; (void)ws_size;
    const float* x   = (const float*)d_in[0];
    const float* Wq  = (const float*)d_in[1];
    const float* Wk  = (const float*)d_in[2];
    const float* Wv  = (const float*)d_in[3];
    const float* Wo  = (const float*)d_in[4];
    const float* g1  = (const float*)d_in[5];
    const float* b1  = (const float*)d_in[6];
    const float* g2  = (const float*)d_in[7];
    const float* b2  = (const float*)d_in[8];
    const float* W1  = (const float*)d_in[9];
    const float* bW1 = (const float*)d_in[10];
    const float* W2  = (const float*)d_in[11];
    const float* bW2 = (const float*)d_in[12];
    float* out = (float*)d_out;

    char* ws = (char*)d_ws;
    // ws layout (bytes):
    //   wt_qkv [2304][768] bf16 : 0        .. 3538944
    //   wt_o   [ 768][768] bf16 : 3538944  .. 4718592
    //   wt_1   [3072][768] bf16 : 4718592  .. 9437184
    //   wt_2   [768][3072] bf16 : 9437184  .. 14155776
    //   slotA  (h1 / attn_out / h2) [8192][768] bf16 : 14155776 .. 26738688
    //   slotB: qkv [8192][2304] bf16 @26738688, vt [96][64][1024] @64487424
    //          (ffn mid [8192][3072] bf16 reuses slotB)          .. 77070336
    unsigned short* wt_qkv = (unsigned short*)(ws);
    unsigned short* wt_o   = (unsigned short*)(ws + 3538944);
    unsigned short* wt_1   = (unsigned short*)(ws + 4718592);
    unsigned short* wt_2   = (unsigned short*)(ws + 9437184);
    unsigned short* slotA  = (unsigned short*)(ws + 14155776);
    unsigned short* qkv    = (unsigned short*)(ws + 26738688);
    unsigned short* vt     = (unsigned short*)(ws + 64487424);
    unsigned short* ffm    = qkv;

    dim3 tb(32, 8);
    wtrans_kernel<<<dim3(24,24), tb, 0, stream>>>(Wq, wt_qkv,             768, 768);
    wtrans_kernel<<<dim3(24,24), tb, 0, stream>>>(Wk, wt_qkv + 768*768,   768, 768);
    wtrans_kernel<<<dim3(24,24), tb, 0, stream>>>(Wv, wt_qkv + 2*768*768, 768, 768);
    wtrans_kernel<<<dim3(24,24), tb, 0, stream>>>(Wo, wt_o,               768, 768);
    wtrans_kernel<<<dim3(96,24), tb, 0, stream>>>(W1, wt_1,               768, 3072);
    wtrans_kernel<<<dim3(24,96), tb, 0, stream>>>(W2, wt_2,               3072, 768);

    ln_kernel<<<M_, 256, 0, stream>>>(x, g1, b1, slotA);
    gemm_kernel<0><<<64*18, 256, 0, stream>>>(slotA, wt_qkv, nullptr, nullptr, qkv, 2304, 768);
    vtrans_kernel<<<1536, 256, 0, stream>>>(qkv, vt);
    attn_kernel<<<1536, 256, 0, stream>>>(qkv, vt, slotA);
    gemm_kernel<2><<<64*6, 256, 0, stream>>>(slotA, wt_o, nullptr, x, (void*)out, 768, 768);
    ln_kernel<<<M_, 256, 0, stream>>>(out, g2, b2, slotA);
    gemm_kernel<1><<<64*24, 256, 0, stream>>>(slotA, wt_1, bW1, nullptr, ffm, 3072, 768);
    gemm_kernel<2><<<64*6, 256, 0, stream>>>(ffm, wt_2, bW2, out, (void*)out, 768, 3072);
}

// Round 2
// 406.305 us; speedup vs baseline: 1.2574x; 1.2574x over previous
//
#include <hip/hip_runtime.h>
#include <cstdint>
#include <cstddef>

#define B_   8
#define S_   1024
#define D_   768
#define H_   12
#define DK_  64
#define DFF_ 3072
#define M_   (B_*S_)   // 8192 token rows

typedef __attribute__((ext_vector_type(8))) short  short8;
typedef __attribute__((ext_vector_type(8))) __bf16 bf16x8;
typedef __attribute__((ext_vector_type(4))) float  f32x4;

__device__ __forceinline__ unsigned short f2bf(float f) {
    unsigned u = __builtin_bit_cast(unsigned, f);
    u += 0x7FFFu + ((u >> 16) & 1u);           // RNE
    return (unsigned short)(u >> 16);
}

__device__ __forceinline__ f32x4 mfma16(short8 a, short8 b, f32x4 c) {
    return __builtin_amdgcn_mfma_f32_16x16x32_bf16(
        __builtin_bit_cast(bf16x8, a), __builtin_bit_cast(bf16x8, b), c, 0, 0, 0);
}

__device__ __forceinline__ void gload16(const void* g, void* l) {
    auto gp = reinterpret_cast<const __attribute__((address_space(1))) unsigned*>(
        reinterpret_cast<uintptr_t>(g));
    auto lp = reinterpret_cast<__attribute__((address_space(3))) unsigned*>(
        reinterpret_cast<uintptr_t>(l));
    __builtin_amdgcn_global_load_lds(gp, lp, 16, 0, 0);
}

__device__ __forceinline__ float gelu_f(float v) {
    return 0.5f * v * (1.0f + erff(v * 0.70710678118654752f));
}

// ---- weight cast+transpose: W[K][N] fp32 -> Wt[N][K] bf16 ----
__global__ __launch_bounds__(256) void wtrans_kernel(
    const float* __restrict__ W, unsigned short* __restrict__ Wt, int K, int N)
{
    __shared__ float tile[32][33];
    int n0 = blockIdx.x * 32, k0 = blockIdx.y * 32;
    int tx = threadIdx.x, ty = threadIdx.y;   // 32 x 8
#pragma unroll
    for (int j = 0; j < 4; ++j)
        tile[ty + j*8][tx] = W[(size_t)(k0 + ty + j*8) * N + n0 + tx];
    __syncthreads();
#pragma unroll
    for (int j = 0; j < 4; ++j)
        Wt[(size_t)(n0 + ty + j*8) * K + k0 + tx] = f2bf(tile[tx][ty + j*8]);
}

// ---- LayerNorm fp32 -> bf16, one row (768) per block of 256 ----
__global__ __launch_bounds__(256) void ln_kernel(
    const float* __restrict__ x, const float* __restrict__ g,
    const float* __restrict__ b, unsigned short* __restrict__ out)
{
    int row = blockIdx.x, t = threadIdx.x;
    const float* xr = x + (size_t)row * D_;
    float v[3];
#pragma unroll
    for (int i = 0; i < 3; ++i) v[i] = xr[t + i*256];
    float s  = v[0] + v[1] + v[2];
    float ss = v[0]*v[0] + v[1]*v[1] + v[2]*v[2];
#pragma unroll
    for (int d = 1; d < 64; d <<= 1) { s += __shfl_xor(s, d); ss += __shfl_xor(ss, d); }
    __shared__ float red[8];
    int w = t >> 6, lane = t & 63;
    if (lane == 0) { red[w] = s; red[4 + w] = ss; }
    __syncthreads();
    s  = red[0] + red[1] + red[2] + red[3];
    ss = red[4] + red[5] + red[6] + red[7];
    float mu   = s * (1.0f / D_);
    float var  = ss * (1.0f / D_) - mu * mu;
    float rstd = rsqrtf(var + 1e-5f);
    unsigned short* orow = out + (size_t)row * D_;
#pragma unroll
    for (int i = 0; i < 3; ++i) {
        int c = t + i*256;
        orow[c] = f2bf((v[i] - mu) * rstd * g[c] + b[c]);
    }
}

// ---- m97-structure GEMM: C[M,N] = A[M,K](bf16) @ Wt[N,K]^T(bf16) ----
// EPI 0: store bf16 | EPI 1: +bias, gelu, store bf16 | EPI 2: (+bias)+resid, store fp32
template<int EPI>
__global__ __launch_bounds__(256) void gemm_kernel(
    const unsigned short* __restrict__ A, const unsigned short* __restrict__ Wt,
    const float* __restrict__ bias, const float* __restrict__ resid,
    void* __restrict__ outp, int N, int K)
{
    __shared__ unsigned short Al[128*32];
    __shared__ unsigned short Bl[128*32];
    const int nbn = N >> 7;
    const int nwg = gridDim.x;
    const int p = blockIdx.x;
    const int bid = (p & 7) * (nwg >> 3) + (p >> 3);   // XCD swizzle (nwg % 8 == 0)
    const int bm = bid / nbn, bn = bid % nbn;
    const int t = threadIdx.x;
    const int lane = t & 63, w = t >> 6;
    const int wm = w >> 1, wn = w & 1;
    const int lr = lane & 15, lh = lane >> 4;
    const int rowS = t >> 2, colS = (t & 3) << 3;   // staging: 4 threads/row, 16B each
    const unsigned short* ag = A  + (size_t)(bm*128 + rowS) * K + colS;
    const unsigned short* bg = Wt + (size_t)(bn*128 + rowS) * K + colS;

    f32x4 acc[4][4] = {};

    for (int k0 = 0; k0 < K; k0 += 32) {
        gload16(ag + k0,                 &Al[t*8]);
        gload16(ag + (size_t)64*K + k0,  &Al[2048 + t*8]);
        gload16(bg + k0,                 &Bl[t*8]);
        gload16(bg + (size_t)64*K + k0,  &Bl[2048 + t*8]);
        __syncthreads();
        short8 af[4], bf[4];
#pragma unroll
        for (int i = 0; i < 4; ++i)
            af[i] = *reinterpret_cast<const short8*>(&Al[(wm*64 + i*16 + lr)*32 + lh*8]);
#pragma unroll
        for (int j = 0; j < 4; ++j)
            bf[j] = *reinterpret_cast<const short8*>(&Bl[(wn*64 + j*16 + lr)*32 + lh*8]);
#pragma unroll
        for (int i = 0; i < 4; ++i)
#pragma unroll
            for (int j = 0; j < 4; ++j)
                acc[i][j] = mfma16(af[i], bf[j], acc[i][j]);
        __syncthreads();
    }

#pragma unroll
    for (int i = 0; i < 4; ++i) {
#pragma unroll
        for (int r = 0; r < 4; ++r) {
            int row = bm*128 + wm*64 + i*16 + lh*4 + r;
#pragma unroll
            for (int j = 0; j < 4; ++j) {
                int col = bn*128 + wn*64 + j*16 + lr;
                float v = acc[i][j][r];
                if (EPI == 0) {
                    ((unsigned short*)outp)[(size_t)row*N + col] = f2bf(v);
                } else if (EPI == 1) {
                    v += bias[col];
                    v = gelu_f(v);
                    ((unsigned short*)outp)[(size_t)row*N + col] = f2bf(v);
                } else {
                    if (bias) v += bias[col];
                    v += resid[(size_t)row*N + col];
                    ((float*)outp)[(size_t)row*N + col] = v;
                }
            }
        }
    }
}

// ---- V transpose: qkv v-section [b,s,h,dk] -> vt[bh][dk][s] ----
__global__ __launch_bounds__(256) void vtrans_kernel(
    const unsigned short* __restrict__ qkv, unsigned short* __restrict__ vt)
{
    __shared__ unsigned short tl[64][65];
    int bid = blockIdx.x;
    int sblk = bid & 15, bh = bid >> 4;
    int b = bh / H_, h = bh % H_;
    int t = threadIdx.x, tx = t & 63, ty = t >> 6;
    int s0 = sblk * 64;
#pragma unroll
    for (int j = 0; j < 16; ++j) {
        int s = j*4 + ty;
        tl[s][tx] = qkv[(size_t)(b*S_ + s0 + s)*2304 + 1536 + h*64 + tx];
    }
    __syncthreads();
#pragma unroll
    for (int j = 0; j < 16; ++j) {
        int dk = j*4 + ty;
        vt[((size_t)bh*64 + dk)*S_ + s0 + tx] = tl[tx][dk];
    }
}

// ---- flash attention v2: per block (b,h,128 q-rows), 4 waves x 32 q-rows ----
// K,V tiles (64 kv) cooperatively staged in LDS (double-buffered, XOR-swizzled),
// 2-phase prefetch with raw barriers; softmax in exp2 domain with defer-max.
__global__ __launch_bounds__(256) void attn_kernel(
    const unsigned short* __restrict__ qkv, const unsigned short* __restrict__ vt,
    unsigned short* __restrict__ out)
{
    __shared__ unsigned short Kl[2][64*64];   // [kv][dk], 8KB per buf, swizzled
    __shared__ unsigned short Vl[2][64*64];   // [dk][kv], 8KB per buf, swizzled
    __shared__ unsigned short Pl[4][16*64];   // per-wave P scratch (swizzled)

    const int p = blockIdx.x;
    const int l = (p & 7) * 96 + (p >> 3);    // XCD swizzle: 768 % 8 == 0
    const int qb = l & 7, bh = l >> 3;
    const int b = bh / H_, h = bh % H_;
    const int t = threadIdx.x, lane = t & 63, w = t >> 6;
    const int lr = lane & 15, lh = lane >> 4;

    const float SC = 0.125f * 1.44269504089f;   // DK^-0.5 * log2(e)

    // Q A-fragments: 2 blocks of 16 q-rows per wave
    const int qrow0 = qb*128 + w*32;
    short8 aq[2][2];
#pragma unroll
    for (int qi = 0; qi < 2; ++qi) {
        const unsigned short* qp = qkv + (size_t)(b*S_ + qrow0 + qi*16 + lr)*2304 + h*64;
#pragma unroll
        for (int c = 0; c < 2; ++c)
            aq[qi][c] = *reinterpret_cast<const short8*>(&qp[c*32 + lh*8]);
    }

    float m_run[2][4], l_run[2][4];
    f32x4 o[2][4] = {};
#pragma unroll
    for (int qi = 0; qi < 2; ++qi)
#pragma unroll
        for (int r = 0; r < 4; ++r) { m_run[qi][r] = -1e30f; l_run[qi][r] = 0.0f; }

    const char* kgbase = (const char*)qkv;
    const char* vgbase = (const char*)vt;
    unsigned short* pw = &Pl[w][0];

    auto stage = [&](int kb, int buf) {
        const int ks = kb * 64;
#pragma unroll
        for (int shot = 0; shot < 2; ++shot) {
            int d = shot*4096 + t*16;         // linear dest byte in 8KB tile
            int row = d >> 7;                  // 128 B per row
            int colb = d & 127;
            int sc = colb ^ ((row & 7) << 4);  // pre-swizzled source (involution)
            const char* ksrc = kgbase + ((size_t)(b*S_ + ks + row)*2304 + 768 + h*64)*2 + sc;
            gload16(ksrc, (char*)&Kl[buf][0] + d);
            const char* vsrc = vgbase + ((size_t)(bh*64 + row)*1024 + ks)*2 + sc;
            gload16(vsrc, (char*)&Vl[buf][0] + d);
        }
    };

    stage(0, 0);
    asm volatile("s_waitcnt vmcnt(0)" ::: "memory");
    __builtin_amdgcn_s_barrier();

    for (int kb = 0; kb < 16; ++kb) {
        const int buf = kb & 1;
        if (kb < 15) stage(kb + 1, buf ^ 1);

        // K B-fragments from LDS (shared by both qi)
        short8 bk[4][2];
#pragma unroll
        for (int j = 0; j < 4; ++j)
#pragma unroll
            for (int c = 0; c < 2; ++c)
                bk[j][c] = *reinterpret_cast<const short8*>(
                    &Kl[buf][(j*16 + lr)*64 + ((c*32 + lh*8) ^ ((lr & 7) << 3))]);

#pragma unroll
        for (int qi = 0; qi < 2; ++qi) {
            // QK^T: S[q=lh*4+r][k=j*16+lr], scaled into log2 domain
            f32x4 s[4];
            __builtin_amdgcn_s_setprio(1);
#pragma unroll
            for (int j = 0; j < 4; ++j) {
                f32x4 z = {0.f, 0.f, 0.f, 0.f};
                z = mfma16(aq[qi][0], bk[j][0], z);
                z = mfma16(aq[qi][1], bk[j][1], z);
                s[j] = z * SC;
            }
            __builtin_amdgcn_s_setprio(0);

            // row max over k: in-lane over j, cross-lane over lr
            float mt[4];
#pragma unroll
            for (int r = 0; r < 4; ++r)
                mt[r] = fmaxf(fmaxf(s[0][r], s[1][r]), fmaxf(s[2][r], s[3][r]));
#pragma unroll
            for (int d = 1; d < 16; d <<= 1)
#pragma unroll
                for (int r = 0; r < 4; ++r) mt[r] = fmaxf(mt[r], __shfl_xor(mt[r], d));

            // defer-max (T13): rescale only if any row grew past THR=8 (log2 domain)
            bool grow = false;
#pragma unroll
            for (int r = 0; r < 4; ++r) grow |= (mt[r] > m_run[qi][r] + 8.0f);
            if (__any(grow)) {
#pragma unroll
                for (int r = 0; r < 4; ++r) {
                    float mn = fmaxf(m_run[qi][r], mt[r]);
                    float a  = exp2f(m_run[qi][r] - mn);
                    m_run[qi][r] = mn;
                    l_run[qi][r] *= a;
#pragma unroll
                    for (int j = 0; j < 4; ++j) o[qi][j][r] *= a;
                }
            }

            // P = 2^(s-m), accumulate row sum, write to per-wave swizzled LDS
            float rs[4] = {0.f, 0.f, 0.f, 0.f};
#pragma unroll
            for (int j = 0; j < 4; ++j)
#pragma unroll
                for (int r = 0; r < 4; ++r) {
                    float pv = exp2f(s[j][r] - m_run[qi][r]);
                    rs[r] += pv;
                    int prow = lh*4 + r;
                    int pcol = (j*16 + lr) ^ ((prow & 7) << 3);
                    pw[prow*64 + pcol] = f2bf(pv);
                }
#pragma unroll
            for (int d = 1; d < 16; d <<= 1)
#pragma unroll
                for (int r = 0; r < 4; ++r) rs[r] += __shfl_xor(rs[r], d);
#pragma unroll
            for (int r = 0; r < 4; ++r) l_run[qi][r] += rs[r];

            // P back as A-frags; V B-frags; PV
            short8 pa[2];
#pragma unroll
            for (int c = 0; c < 2; ++c)
                pa[c] = *reinterpret_cast<const short8*>(
                    &pw[lr*64 + ((c*32 + lh*8) ^ ((lr & 7) << 3))]);
            __builtin_amdgcn_s_setprio(1);
#pragma unroll
            for (int j = 0; j < 4; ++j) {
                short8 bv0 = *reinterpret_cast<const short8*>(
                    &Vl[buf][(j*16 + lr)*64 + ((lh*8) ^ ((lr & 7) << 3))]);
                short8 bv1 = *reinterpret_cast<const short8*>(
                    &Vl[buf][(j*16 + lr)*64 + ((32 + lh*8) ^ ((lr & 7) << 3))]);
                o[qi][j] = mfma16(pa[0], bv0, o[qi][j]);
                o[qi][j] = mfma16(pa[1], bv1, o[qi][j]);
            }
            __builtin_amdgcn_s_setprio(0);
        }

        asm volatile("s_waitcnt vmcnt(0)" ::: "memory");
        __builtin_amdgcn_s_barrier();
    }

#pragma unroll
    for (int qi = 0; qi < 2; ++qi)
#pragma unroll
        for (int j = 0; j < 4; ++j)
#pragma unroll
            for (int r = 0; r < 4; ++r) {
                float v = o[qi][j][r] / l_run[qi][r];
                int row = qrow0 + qi*16 + lh*4 + r;
                int col = h*64 + j*16 + lr;
                out[(size_t)(b*S_ + row)*D_ + col] = f2bf(v);
            }
}

extern "C" void kernel_launch(void* const* d_in, const int* in_sizes, int n_in,
                              void* d_out, int out_size, void* d_ws, size_t ws_size,
                              hipStream_t stream)
{
    (void)in_sizes; (void)n_in; (void)out_size; (void)ws_size;
    const float* x   = (const float*)d_in[0];
    const float* Wq  = (const float*)d_in[1];
    const float* Wk  = (const float*)d_in[2];
    const float* Wv  = (const float*)d_in[3];
    const float* Wo  = (const float*)d_in[4];
    const float* g1  = (const float*)d_in[5];
    const float* b1  = (const float*)d_in[6];
    const float* g2  = (const float*)d_in[7];
    const float* b2  = (const float*)d_in[8];
    const float* W1  = (const float*)d_in[9];
    const float* bW1 = (const float*)d_in[10];
    const float* W2  = (const float*)d_in[11];
    const float* bW2 = (const float*)d_in[12];
    float* out = (float*)d_out;

    char* ws = (char*)d_ws;
    unsigned short* wt_qkv = (unsigned short*)(ws);
    unsigned short* wt_o   = (unsigned short*)(ws + 3538944);
    unsigned short* wt_1   = (unsigned short*)(ws + 4718592);
    unsigned short* wt_2   = (unsigned short*)(ws + 9437184);
    unsigned short* slotA  = (unsigned short*)(ws + 14155776);
    unsigned short* qkv    = (unsigned short*)(ws + 26738688);
    unsigned short* vt     = (unsigned short*)(ws + 64487424);
    unsigned short* ffm    = qkv;

    dim3 tb(32, 8);
    wtrans_kernel<<<dim3(24,24), tb, 0, stream>>>(Wq, wt_qkv,             768, 768);
    wtrans_kernel<<<dim3(24,24), tb, 0, stream>>>(Wk, wt_qkv + 768*768,   768, 768);
    wtrans_kernel<<<dim3(24,24), tb, 0, stream>>>(Wv, wt_qkv + 2*768*768, 768, 768);
    wtrans_kernel<<<dim3(24,24), tb, 0, stream>>>(Wo, wt_o,               768, 768);
    wtrans_kernel<<<dim3(96,24), tb, 0, stream>>>(W1, wt_1,               768, 3072);
    wtrans_kernel<<<dim3(24,96), tb, 0, stream>>>(W2, wt_2,               3072, 768);

    ln_kernel<<<M_, 256, 0, stream>>>(x, g1, b1, slotA);
    gemm_kernel<0><<<64*18, 256, 0, stream>>>(slotA, wt_qkv, nullptr, nullptr, qkv, 2304, 768);
    vtrans_kernel<<<1536, 256, 0, stream>>>(qkv, vt);
    attn_kernel<<<768, 256, 0, stream>>>(qkv, vt, slotA);
    gemm_kernel<2><<<64*6, 256, 0, stream>>>(slotA, wt_o, nullptr, x, (void*)out, 768, 768);
    ln_kernel<<<M_, 256, 0, stream>>>(out, g2, b2, slotA);
    gemm_kernel<1><<<64*24, 256, 0, stream>>>(slotA, wt_1, bW1, nullptr, ffm, 3072, 768);
    gemm_kernel<2><<<64*6, 256, 0, stream>>>(ffm, wt_2, bW2, out, (void*)out, 768, 3072);
}

// Round 3
// 324.050 us; speedup vs baseline: 1.5766x; 1.2538x over previous
//
#include <hip/hip_runtime.h>
#include <cstdint>
#include <cstddef>

#define B_   8
#define S_   1024
#define D_   768
#define H_   12
#define DK_  64
#define DFF_ 3072
#define M_   (B_*S_)   // 8192 token rows

typedef __attribute__((ext_vector_type(8))) short  short8;
typedef __attribute__((ext_vector_type(4))) short  short4v;
typedef __attribute__((ext_vector_type(8))) __bf16 bf16x8;
typedef __attribute__((ext_vector_type(4))) float  f32x4;
typedef __attribute__((ext_vector_type(4))) unsigned uint4v;
typedef __attribute__((ext_vector_type(2))) unsigned uint2v;

__device__ __forceinline__ unsigned short f2bf(float f) {
    unsigned u = __builtin_bit_cast(unsigned, f);
    u += 0x7FFFu + ((u >> 16) & 1u);           // RNE
    return (unsigned short)(u >> 16);
}

__device__ __forceinline__ unsigned pkbf(float a, float b) {
    unsigned short ua = __builtin_bit_cast(unsigned short, (__bf16)a);
    unsigned short ub = __builtin_bit_cast(unsigned short, (__bf16)b);
    return (unsigned)ua | ((unsigned)ub << 16);
}

__device__ __forceinline__ f32x4 mfma16(short8 a, short8 b, f32x4 c) {
    return __builtin_amdgcn_mfma_f32_16x16x32_bf16(
        __builtin_bit_cast(bf16x8, a), __builtin_bit_cast(bf16x8, b), c, 0, 0, 0);
}

__device__ __forceinline__ void gload16(const void* g, void* l) {
    auto gp = reinterpret_cast<const __attribute__((address_space(1))) unsigned*>(
        reinterpret_cast<uintptr_t>(g));
    auto lp = reinterpret_cast<__attribute__((address_space(3))) unsigned*>(
        reinterpret_cast<uintptr_t>(l));
    __builtin_amdgcn_global_load_lds(gp, lp, 16, 0, 0);
}

__device__ __forceinline__ float gelu_f(float v) {
    return 0.5f * v * (1.0f + erff(v * 0.70710678118654752f));
}

// ---- fused weight cast+transpose for the four 768x768 weights ----
__global__ __launch_bounds__(256) void wtrans4_kernel(
    const float* __restrict__ W0, const float* __restrict__ W1,
    const float* __restrict__ W2, const float* __restrict__ W3,
    unsigned short* __restrict__ Wt)   // [4][768][768] dst
{
    __shared__ float tile[32][33];
    int z = blockIdx.z;
    const float* W = (z == 0) ? W0 : (z == 1) ? W1 : (z == 2) ? W2 : W3;
    unsigned short* dst = Wt + (size_t)z * 768 * 768;
    int n0 = blockIdx.x * 32, k0 = blockIdx.y * 32;
    int tx = threadIdx.x, ty = threadIdx.y;   // 32 x 8
#pragma unroll
    for (int j = 0; j < 4; ++j)
        tile[ty + j*8][tx] = W[(size_t)(k0 + ty + j*8) * 768 + n0 + tx];
    __syncthreads();
#pragma unroll
    for (int j = 0; j < 4; ++j)
        dst[(size_t)(n0 + ty + j*8) * 768 + k0 + tx] = f2bf(tile[tx][ty + j*8]);
}

// ---- weight cast+transpose: W[K][N] fp32 -> Wt[N][K] bf16 ----
__global__ __launch_bounds__(256) void wtrans_kernel(
    const float* __restrict__ W, unsigned short* __restrict__ Wt, int K, int N)
{
    __shared__ float tile[32][33];
    int n0 = blockIdx.x * 32, k0 = blockIdx.y * 32;
    int tx = threadIdx.x, ty = threadIdx.y;   // 32 x 8
#pragma unroll
    for (int j = 0; j < 4; ++j)
        tile[ty + j*8][tx] = W[(size_t)(k0 + ty + j*8) * N + n0 + tx];
    __syncthreads();
#pragma unroll
    for (int j = 0; j < 4; ++j)
        Wt[(size_t)(n0 + ty + j*8) * K + k0 + tx] = f2bf(tile[tx][ty + j*8]);
}

// ---- LayerNorm fp32 -> bf16, one row (768) per block of 256 ----
__global__ __launch_bounds__(256) void ln_kernel(
    const float* __restrict__ x, const float* __restrict__ g,
    const float* __restrict__ b, unsigned short* __restrict__ out)
{
    int row = blockIdx.x, t = threadIdx.x;
    const float* xr = x + (size_t)row * D_;
    float v[3];
#pragma unroll
    for (int i = 0; i < 3; ++i) v[i] = xr[t + i*256];
    float s  = v[0] + v[1] + v[2];
    float ss = v[0]*v[0] + v[1]*v[1] + v[2]*v[2];
#pragma unroll
    for (int d = 1; d < 64; d <<= 1) { s += __shfl_xor(s, d); ss += __shfl_xor(ss, d); }
    __shared__ float red[8];
    int w = t >> 6, lane = t & 63;
    if (lane == 0) { red[w] = s; red[4 + w] = ss; }
    __syncthreads();
    s  = red[0] + red[1] + red[2] + red[3];
    ss = red[4] + red[5] + red[6] + red[7];
    float mu   = s * (1.0f / D_);
    float var  = ss * (1.0f / D_) - mu * mu;
    float rstd = rsqrtf(var + 1e-5f);
    unsigned short* orow = out + (size_t)row * D_;
#pragma unroll
    for (int i = 0; i < 3; ++i) {
        int c = t + i*256;
        orow[c] = f2bf((v[i] - mu) * rstd * g[c] + b[c]);
    }
}

// ---- dbuf GEMM: C[M,N] = A[M,K](bf16) @ Wt[N,K]^T(bf16), BM=128, BN=128|64 ----
// 2-phase: stage(next) issued before compute(cur); one vmcnt(0)+barrier per step.
// EPI 0: store bf16 | EPI 1: +bias, gelu, store bf16 | EPI 2: (+bias)+resid, fp32
template<int BN, int EPI>
__global__ __launch_bounds__(256) void gemm_kernel(
    const unsigned short* __restrict__ A, const unsigned short* __restrict__ Wt,
    const float* __restrict__ bias, const float* __restrict__ resid,
    void* __restrict__ outp, int N, int K)
{
    __shared__ unsigned short Al[2][128*32];
    __shared__ unsigned short Bl[2][BN*32];
    constexpr int NJ = BN / 64;               // 2 or 1
    const int nbn = N / BN;
    const int nwg = gridDim.x;
    const int p = blockIdx.x;
    const int bid = (p & 7) * (nwg >> 3) + (p >> 3);   // XCD swizzle (nwg % 8 == 0)
    const int bm = bid / nbn, bn = bid % nbn;
    const int t = threadIdx.x;
    const int lane = t & 63, w = t >> 6;
    const int wm = w >> 1, wn = w & 1;
    const int lr = lane & 15, lh = lane >> 4;
    const int rowS = t >> 2, colS = (t & 3) << 3;   // staging: 4 threads/row, 16B each
    const unsigned short* ag = A  + (size_t)(bm*128 + rowS) * K + colS;
    const unsigned short* bg = Wt + (size_t)(bn*BN  + rowS) * K + colS;

    f32x4 acc[4][2*NJ] = {};

    auto stage = [&](int k0, int buf) {
        gload16(ag + k0,                &Al[buf][t*8]);
        gload16(ag + (size_t)64*K + k0, &Al[buf][2048 + t*8]);
        gload16(bg + k0,                &Bl[buf][t*8]);
        if constexpr (BN == 128)
            gload16(bg + (size_t)64*K + k0, &Bl[buf][2048 + t*8]);
    };

    const int nk = K >> 5;
    stage(0, 0);
    asm volatile("s_waitcnt vmcnt(0)" ::: "memory");
    __builtin_amdgcn_s_barrier();

    for (int it = 0; it < nk; ++it) {
        const int buf = it & 1;
        if (it + 1 < nk) stage((it + 1) << 5, buf ^ 1);
        short8 af[4], bf[2*NJ];
#pragma unroll
        for (int i = 0; i < 4; ++i)
            af[i] = *reinterpret_cast<const short8*>(&Al[buf][(wm*64 + i*16 + lr)*32 + lh*8]);
#pragma unroll
        for (int j = 0; j < 2*NJ; ++j)
            bf[j] = *reinterpret_cast<const short8*>(&Bl[buf][(wn*(32*NJ) + j*16 + lr)*32 + lh*8]);
        __builtin_amdgcn_s_setprio(1);
#pragma unroll
        for (int i = 0; i < 4; ++i)
#pragma unroll
            for (int j = 0; j < 2*NJ; ++j)
                acc[i][j] = mfma16(af[i], bf[j], acc[i][j]);
        __builtin_amdgcn_s_setprio(0);
        asm volatile("s_waitcnt vmcnt(0)" ::: "memory");
        __builtin_amdgcn_s_barrier();
    }

#pragma unroll
    for (int i = 0; i < 4; ++i) {
#pragma unroll
        for (int r = 0; r < 4; ++r) {
            int row = bm*128 + wm*64 + i*16 + lh*4 + r;
#pragma unroll
            for (int j = 0; j < 2*NJ; ++j) {
                int col = bn*BN + wn*(32*NJ) + j*16 + lr;
                float v = acc[i][j][r];
                if (EPI == 0) {
                    ((unsigned short*)outp)[(size_t)row*N + col] = f2bf(v);
                } else if (EPI == 1) {
                    v += bias[col];
                    v = gelu_f(v);
                    ((unsigned short*)outp)[(size_t)row*N + col] = f2bf(v);
                } else {
                    if (bias) v += bias[col];
                    v += resid[(size_t)row*N + col];
                    ((float*)outp)[(size_t)row*N + col] = v;
                }
            }
        }
    }
}

// ---- V transpose: qkv v-section [b,s,h,dk] -> vt[bh][dk][s] ----
__global__ __launch_bounds__(256) void vtrans_kernel(
    const unsigned short* __restrict__ qkv, unsigned short* __restrict__ vt)
{
    __shared__ unsigned short tl[64][65];
    int bid = blockIdx.x;
    int sblk = bid & 15, bh = bid >> 4;
    int b = bh / H_, h = bh % H_;
    int t = threadIdx.x, tx = t & 63, ty = t >> 6;
    int s0 = sblk * 64;
#pragma unroll
    for (int j = 0; j < 16; ++j) {
        int s = j*4 + ty;
        tl[s][tx] = qkv[(size_t)(b*S_ + s0 + s)*2304 + 1536 + h*64 + tx];
    }
    __syncthreads();
#pragma unroll
    for (int j = 0; j < 16; ++j) {
        int dk = j*4 + ty;
        vt[((size_t)bh*64 + dk)*S_ + s0 + tx] = tl[tx][dk];
    }
}

// ---- flash attention v3: swapped-operand QK^T (S^T), in-register P ----
// Per block: (b,h,128 q-rows), 4 waves x 32 q. K,V staged in LDS (dbuf, swizzled).
// P's natural packed layout defines k-permutation pi; V a-frags apply pi at
// LDS-read time (2x ds_read_b64) -> no P shuffles, no P LDS roundtrip.
__global__ __launch_bounds__(256, 3) void attn_kernel(
    const unsigned short* __restrict__ qkv, const unsigned short* __restrict__ vt,
    unsigned short* __restrict__ out)
{
    __shared__ unsigned short Kl[2][64*64];   // [kv][dk], swizzled
    __shared__ unsigned short Vl[2][64*64];   // [dk][kv], swizzled

    const int p = blockIdx.x;
    const int l = (p & 7) * 96 + (p >> 3);    // XCD swizzle: 768 % 8 == 0
    const int qb = l & 7, bh = l >> 3;
    const int b = bh / H_, h = bh % H_;
    const int t = threadIdx.x, lane = t & 63, w = t >> 6;
    const int lr = lane & 15, lh = lane >> 4;
    const int sz = (lr & 7) << 3;             // XOR swizzle (ushort units)

    const float SC = 0.125f * 1.44269504089f; // DK^-0.5 * log2(e)

    // Q as B-fragments (col = q = lr): bq[qi][c]
    const int qrow0 = qb*128 + w*32;
    short8 bq[2][2];
#pragma unroll
    for (int qi = 0; qi < 2; ++qi) {
        const unsigned short* qp = qkv + (size_t)(b*S_ + qrow0 + qi*16 + lr)*2304 + h*64;
#pragma unroll
        for (int c = 0; c < 2; ++c)
            bq[qi][c] = *reinterpret_cast<const short8*>(&qp[c*32 + lh*8]);
    }

    float m_run[2] = {-1e30f, -1e30f};
    float l_run[2] = {0.f, 0.f};              // per-lane partial (cross-lh deferred)
    f32x4 o[2][4] = {};                       // O^T: row d=j*16+lh*4+r, col q=lr

    const char* kgbase = (const char*)qkv;
    const char* vgbase = (const char*)vt;

    auto stage = [&](int kb, int buf) {
        const int ks = kb * 64;
#pragma unroll
        for (int shot = 0; shot < 2; ++shot) {
            int d = shot*4096 + t*16;          // linear dest byte in 8KB tile
            int row = d >> 7;                  // 128 B per row
            int colb = d & 127;
            int sc = colb ^ ((row & 7) << 4);  // pre-swizzled source (involution)
            const char* ksrc = kgbase + ((size_t)(b*S_ + ks + row)*2304 + 768 + h*64)*2 + sc;
            gload16(ksrc, (char*)&Kl[buf][0] + d);
            const char* vsrc = vgbase + ((size_t)(bh*64 + row)*1024 + ks)*2 + sc;
            gload16(vsrc, (char*)&Vl[buf][0] + d);
        }
    };

    stage(0, 0);
    asm volatile("s_waitcnt vmcnt(0)" ::: "memory");
    __builtin_amdgcn_s_barrier();

    for (int kb = 0; kb < 16; ++kb) {
        const int buf = kb & 1;
        if (kb < 15) stage(kb + 1, buf ^ 1);

        // K as A-fragments (rows = k_local)
        short8 ak[4][2];
#pragma unroll
        for (int j = 0; j < 4; ++j)
#pragma unroll
            for (int c = 0; c < 2; ++c)
                ak[j][c] = *reinterpret_cast<const short8*>(
                    &Kl[buf][(j*16 + lr)*64 + ((c*32 + lh*8) ^ sz)]);

        // V as A-fragments with pi permutation: av[j][ks], two b64 reads each
        short8 av[4][2];
#pragma unroll
        for (int j = 0; j < 4; ++j) {
            const unsigned short* vrow = &Vl[buf][(j*16 + lr)*64];
#pragma unroll
            for (int ks = 0; ks < 2; ++ks) {
                short4v lo = *reinterpret_cast<const short4v*>(&vrow[(ks*32 + lh*4)      ^ sz]);
                short4v hi = *reinterpret_cast<const short4v*>(&vrow[(ks*32 + 16 + lh*4) ^ sz]);
                av[j][ks] = __builtin_shufflevector(lo, hi, 0,1,2,3,4,5,6,7);
            }
        }

#pragma unroll
        for (int qi = 0; qi < 2; ++qi) {
            // S^T = K·Q: row = k_local = j*16+lh*4+r, col = q = lr (raw, unscaled)
            f32x4 s[4];
            __builtin_amdgcn_s_setprio(1);
#pragma unroll
            for (int j = 0; j < 4; ++j) {
                f32x4 z = {0.f, 0.f, 0.f, 0.f};
                z = mfma16(ak[j][0], bq[qi][0], z);
                z = mfma16(ak[j][1], bq[qi][1], z);
                s[j] = z;
            }
            __builtin_amdgcn_s_setprio(0);

            // in-lane max over 16 raw values, scale once, 2 cross-lh shuffles
            float m01 = fmaxf(fmaxf(s[0][0], s[0][1]), fmaxf(s[0][2], s[0][3]));
            float m1  = fmaxf(fmaxf(s[1][0], s[1][1]), fmaxf(s[1][2], s[1][3]));
            float m2  = fmaxf(fmaxf(s[2][0], s[2][1]), fmaxf(s[2][2], s[2][3]));
            float m3  = fmaxf(fmaxf(s[3][0], s[3][1]), fmaxf(s[3][2], s[3][3]));
            float mt = fmaxf(fmaxf(m01, m1), fmaxf(m2, m3)) * SC;
            mt = fmaxf(mt, __shfl_xor(mt, 16));
            mt = fmaxf(mt, __shfl_xor(mt, 32));

            // defer-max (T13, THR=8 in log2 domain)
            if (__any(mt > m_run[qi] + 8.0f)) {
                float mn = fmaxf(m_run[qi], mt);
                float a  = exp2f(m_run[qi] - mn);
                m_run[qi] = mn;
                l_run[qi] *= a;
#pragma unroll
                for (int j = 0; j < 4; ++j)
#pragma unroll
                    for (int r = 0; r < 4; ++r) o[qi][j][r] *= a;
            }

            // P = 2^(s*SC - m); in-lane partial row sum
            const float negm = -m_run[qi];
            float rs = 0.f;
#pragma unroll
            for (int j = 0; j < 4; ++j)
#pragma unroll
                for (int r = 0; r < 4; ++r) {
                    float pv = exp2f(__builtin_fmaf(s[j][r], SC, negm));
                    s[j][r] = pv;
                    rs += pv;
                }
            l_run[qi] += rs;

            // pack P -> B-fragments (natural layout; pi applied on V side)
            uint4v u0 = { pkbf(s[0][0], s[0][1]), pkbf(s[0][2], s[0][3]),
                          pkbf(s[1][0], s[1][1]), pkbf(s[1][2], s[1][3]) };
            uint4v u1 = { pkbf(s[2][0], s[2][1]), pkbf(s[2][2], s[2][3]),
                          pkbf(s[3][0], s[3][1]), pkbf(s[3][2], s[3][3]) };
            short8 pb0 = __builtin_bit_cast(short8, u0);
            short8 pb1 = __builtin_bit_cast(short8, u1);

            __builtin_amdgcn_s_setprio(1);
#pragma unroll
            for (int j = 0; j < 4; ++j) {
                o[qi][j] = mfma16(av[j][0], pb0, o[qi][j]);
                o[qi][j] = mfma16(av[j][1], pb1, o[qi][j]);
            }
            __builtin_amdgcn_s_setprio(0);
        }

        asm volatile("s_waitcnt vmcnt(0)" ::: "memory");
        __builtin_amdgcn_s_barrier();
    }

    // epilogue: finish l reduction across lh, normalize, vectorized 8B stores
#pragma unroll
    for (int qi = 0; qi < 2; ++qi) {
        float ls = l_run[qi];
        ls += __shfl_xor(ls, 16);
        ls += __shfl_xor(ls, 32);
        float inv = 1.0f / ls;
        int q = qrow0 + qi*16 + lr;
        unsigned short* orow = out + (size_t)(b*S_ + q)*D_ + h*64;
#pragma unroll
        for (int j = 0; j < 4; ++j) {
            uint2v vv = { pkbf(o[qi][j][0]*inv, o[qi][j][1]*inv),
                          pkbf(o[qi][j][2]*inv, o[qi][j][3]*inv) };
            *reinterpret_cast<uint2v*>(&orow[j*16 + lh*4]) = vv;
        }
    }
}

extern "C" void kernel_launch(void* const* d_in, const int* in_sizes, int n_in,
                              void* d_out, int out_size, void* d_ws, size_t ws_size,
                              hipStream_t stream)
{
    (void)in_sizes; (void)n_in; (void)out_size; (void)ws_size;
    const float* x   = (const float*)d_in[0];
    const float* Wq  = (const float*)d_in[1];
    const float* Wk  = (const float*)d_in[2];
    const float* Wv  = (const float*)d_in[3];
    const float* Wo  = (const float*)d_in[4];
    const float* g1  = (const float*)d_in[5];
    const float* b1  = (const float*)d_in[6];
    const float* g2  = (const float*)d_in[7];
    const float* b2  = (const float*)d_in[8];
    const float* W1  = (const float*)d_in[9];
    const float* bW1 = (const float*)d_in[10];
    const float* W2  = (const float*)d_in[11];
    const float* bW2 = (const float*)d_in[12];
    float* out = (float*)d_out;

    char* ws = (char*)d_ws;
    unsigned short* wt_qkv = (unsigned short*)(ws);            // [2304][768] + wt_o after
    unsigned short* wt_o   = (unsigned short*)(ws + 3538944);  // [768][768]
    unsigned short* wt_1   = (unsigned short*)(ws + 4718592);  // [3072][768]
    unsigned short* wt_2   = (unsigned short*)(ws + 9437184);  // [768][3072]
    unsigned short* slotA  = (unsigned short*)(ws + 14155776); // [8192][768] bf16
    unsigned short* qkv    = (unsigned short*)(ws + 26738688); // [8192][2304] bf16
    unsigned short* vt     = (unsigned short*)(ws + 64487424); // [96][64][1024] bf16
    unsigned short* ffm    = qkv;                              // [8192][3072] bf16 (reuse)

    dim3 tb(32, 8);
    // wt_qkv (Wq,Wk,Wv) and wt_o are contiguous: one fused launch
    wtrans4_kernel<<<dim3(24,24,4), tb, 0, stream>>>(Wq, Wk, Wv, Wo, wt_qkv);
    wtrans_kernel<<<dim3(96,24), tb, 0, stream>>>(W1, wt_1, 768, 3072);
    wtrans_kernel<<<dim3(24,96), tb, 0, stream>>>(W2, wt_2, 3072, 768);

    ln_kernel<<<M_, 256, 0, stream>>>(x, g1, b1, slotA);
    gemm_kernel<128,0><<<64*18, 256, 0, stream>>>(slotA, wt_qkv, nullptr, nullptr, qkv, 2304, 768);
    vtrans_kernel<<<1536, 256, 0, stream>>>(qkv, vt);
    attn_kernel<<<768, 256, 0, stream>>>(qkv, vt, slotA);
    gemm_kernel<64,2><<<64*12, 256, 0, stream>>>(slotA, wt_o, nullptr, x, (void*)out, 768, 768);
    ln_kernel<<<M_, 256, 0, stream>>>(out, g2, b2, slotA);
    gemm_kernel<128,1><<<64*24, 256, 0, stream>>>(slotA, wt_1, bW1, nullptr, ffm, 3072, 768);
    gemm_kernel<64,2><<<64*12, 256, 0, stream>>>(ffm, wt_2, bW2, out, (void*)out, 768, 3072);
}

// Round 4
// 305.920 us; speedup vs baseline: 1.6700x; 1.0593x over previous
//
#include <hip/hip_runtime.h>
#include <cstdint>
#include <cstddef>

#define B_   8
#define S_   1024
#define D_   768
#define H_   12
#define DK_  64
#define DFF_ 3072
#define M_   (B_*S_)   // 8192 token rows

typedef __attribute__((ext_vector_type(8))) short  short8;
typedef __attribute__((ext_vector_type(4))) short  short4v;
typedef __attribute__((ext_vector_type(8))) __bf16 bf16x8;
typedef __attribute__((ext_vector_type(4))) float  f32x4;
typedef __attribute__((ext_vector_type(4))) unsigned uint4v;
typedef __attribute__((ext_vector_type(2))) unsigned uint2v;

__device__ __forceinline__ unsigned short f2bf(float f) {
    unsigned u = __builtin_bit_cast(unsigned, f);
    u += 0x7FFFu + ((u >> 16) & 1u);           // RNE
    return (unsigned short)(u >> 16);
}

__device__ __forceinline__ unsigned pkbf(float a, float b) {
    unsigned short ua = __builtin_bit_cast(unsigned short, (__bf16)a);
    unsigned short ub = __builtin_bit_cast(unsigned short, (__bf16)b);
    return (unsigned)ua | ((unsigned)ub << 16);
}

__device__ __forceinline__ f32x4 mfma16(short8 a, short8 b, f32x4 c) {
    return __builtin_amdgcn_mfma_f32_16x16x32_bf16(
        __builtin_bit_cast(bf16x8, a), __builtin_bit_cast(bf16x8, b), c, 0, 0, 0);
}

__device__ __forceinline__ void gload16(const void* g, void* l) {
    auto gp = reinterpret_cast<const __attribute__((address_space(1))) unsigned*>(
        reinterpret_cast<uintptr_t>(g));
    auto lp = reinterpret_cast<__attribute__((address_space(3))) unsigned*>(
        reinterpret_cast<uintptr_t>(l));
    __builtin_amdgcn_global_load_lds(gp, lp, 16, 0, 0);
}

__device__ __forceinline__ float gelu_f(float v) {
    return 0.5f * v * (1.0f + erff(v * 0.70710678118654752f));
}

// ---- fused weight cast+transpose for the four 768x768 weights ----
__global__ __launch_bounds__(256) void wtrans4_kernel(
    const float* __restrict__ W0, const float* __restrict__ W1,
    const float* __restrict__ W2, const float* __restrict__ W3,
    unsigned short* __restrict__ Wt)   // [4][768][768] dst
{
    __shared__ float tile[32][33];
    int z = blockIdx.z;
    const float* W = (z == 0) ? W0 : (z == 1) ? W1 : (z == 2) ? W2 : W3;
    unsigned short* dst = Wt + (size_t)z * 768 * 768;
    int n0 = blockIdx.x * 32, k0 = blockIdx.y * 32;
    int tx = threadIdx.x, ty = threadIdx.y;   // 32 x 8
#pragma unroll
    for (int j = 0; j < 4; ++j)
        tile[ty + j*8][tx] = W[(size_t)(k0 + ty + j*8) * 768 + n0 + tx];
    __syncthreads();
#pragma unroll
    for (int j = 0; j < 4; ++j)
        dst[(size_t)(n0 + ty + j*8) * 768 + k0 + tx] = f2bf(tile[tx][ty + j*8]);
}

// ---- weight cast+transpose: W[K][N] fp32 -> Wt[N][K] bf16 ----
__global__ __launch_bounds__(256) void wtrans_kernel(
    const float* __restrict__ W, unsigned short* __restrict__ Wt, int K, int N)
{
    __shared__ float tile[32][33];
    int n0 = blockIdx.x * 32, k0 = blockIdx.y * 32;
    int tx = threadIdx.x, ty = threadIdx.y;   // 32 x 8
#pragma unroll
    for (int j = 0; j < 4; ++j)
        tile[ty + j*8][tx] = W[(size_t)(k0 + ty + j*8) * N + n0 + tx];
    __syncthreads();
#pragma unroll
    for (int j = 0; j < 4; ++j)
        Wt[(size_t)(n0 + ty + j*8) * K + k0 + tx] = f2bf(tile[tx][ty + j*8]);
}

// ---- LayerNorm fp32 -> bf16, one row (768) per block of 256 ----
__global__ __launch_bounds__(256) void ln_kernel(
    const float* __restrict__ x, const float* __restrict__ g,
    const float* __restrict__ b, unsigned short* __restrict__ out)
{
    int row = blockIdx.x, t = threadIdx.x;
    const float* xr = x + (size_t)row * D_;
    float v[3];
#pragma unroll
    for (int i = 0; i < 3; ++i) v[i] = xr[t + i*256];
    float s  = v[0] + v[1] + v[2];
    float ss = v[0]*v[0] + v[1]*v[1] + v[2]*v[2];
#pragma unroll
    for (int d = 1; d < 64; d <<= 1) { s += __shfl_xor(s, d); ss += __shfl_xor(ss, d); }
    __shared__ float red[8];
    int w = t >> 6, lane = t & 63;
    if (lane == 0) { red[w] = s; red[4 + w] = ss; }
    __syncthreads();
    s  = red[0] + red[1] + red[2] + red[3];
    ss = red[4] + red[5] + red[6] + red[7];
    float mu   = s * (1.0f / D_);
    float var  = ss * (1.0f / D_) - mu * mu;
    float rstd = rsqrtf(var + 1e-5f);
    unsigned short* orow = out + (size_t)row * D_;
#pragma unroll
    for (int i = 0; i < 3; ++i) {
        int c = t + i*256;
        orow[c] = f2bf((v[i] - mu) * rstd * g[c] + b[c]);
    }
}

// ---- pipelined GEMM: C[M,N] = A[M,K](bf16) @ Wt[N,K]^T(bf16) ----
// BM=128, BK=64, BN=128|64. Counted-vmcnt 2-deep pipeline (T4): prologue stages
// tiles 0,1; loop waits vmcnt(NL) (next tile stays in flight), computes, then
// stages tile it+2. LDS rows (128B) XOR-swizzled (T2): chunk ^= row&7, applied
// as inverse-swizzled global source + swizzled ds_read (rule #21).
// EPI 0: store bf16 | EPI 1: +bias, gelu, store bf16 | EPI 2: (+bias)+resid, fp32
template<int BN, int EPI>
__global__ __launch_bounds__(256, 2) void gemm_kernel(
    const unsigned short* __restrict__ A, const unsigned short* __restrict__ Wt,
    const float* __restrict__ bias, const float* __restrict__ resid,
    void* __restrict__ outp, int N, int K)
{
    __shared__ unsigned short Al[2][128*64];
    __shared__ unsigned short Bl[2][BN*64];
    constexpr int NJ = BN / 64;               // 2 or 1
    const int nbn = N / BN;
    const int nwg = gridDim.x;
    const int p = blockIdx.x;
    const int bid = (p & 7) * (nwg >> 3) + (p >> 3);   // XCD swizzle (nwg % 8 == 0)
    const int bm = bid / nbn, bn = bid % nbn;
    const int t = threadIdx.x;
    const int lane = t & 63, w = t >> 6;
    const int wm = w >> 1, wn = w & 1;
    const int lr = lane & 15, lh = lane >> 4;
    const char* aBase = (const char*)(A  + (size_t)(bm*128) * K);
    const char* bBase = (const char*)(Wt + (size_t)(bn*BN)  * K);

    f32x4 acc[4][2*NJ] = {};

    auto stage = [&](int kt, int buf) {
        const int k0b = kt << 7;              // byte offset along K
#pragma unroll
        for (int shot = 0; shot < 4; ++shot) {
            int d = shot*4096 + t*16;
            int row = d >> 7;
            int ch  = ((d >> 4) & 7) ^ (row & 7);
            gload16(aBase + (size_t)row*(K*2) + k0b + ch*16, (char*)&Al[buf][0] + d);
        }
#pragma unroll
        for (int shot = 0; shot < 2*NJ; ++shot) {
            int d = shot*4096 + t*16;
            int row = d >> 7;
            int ch  = ((d >> 4) & 7) ^ (row & 7);
            gload16(bBase + (size_t)row*(K*2) + k0b + ch*16, (char*)&Bl[buf][0] + d);
        }
    };

    const int nk = K >> 6;
    stage(0, 0);
    stage(1, 1);

    for (int it = 0; it < nk; ++it) {
        const int buf = it & 1;
        if (it + 1 < nk) {
            if constexpr (BN == 128) asm volatile("s_waitcnt vmcnt(8)" ::: "memory");
            else                     asm volatile("s_waitcnt vmcnt(6)" ::: "memory");
        } else {
            asm volatile("s_waitcnt vmcnt(0)" ::: "memory");
        }
        __builtin_amdgcn_s_barrier();

        short8 af[2][4], bf[2][2*NJ];
#pragma unroll
        for (int kk = 0; kk < 2; ++kk) {
#pragma unroll
            for (int i = 0; i < 4; ++i)
                af[kk][i] = *reinterpret_cast<const short8*>(
                    &Al[buf][(wm*64 + i*16 + lr)*64 + (((kk*4 + lh) ^ (lr & 7))*8)]);
#pragma unroll
            for (int j = 0; j < 2*NJ; ++j)
                bf[kk][j] = *reinterpret_cast<const short8*>(
                    &Bl[buf][(wn*(32*NJ) + j*16 + lr)*64 + (((kk*4 + lh) ^ (lr & 7))*8)]);
        }
        __builtin_amdgcn_s_setprio(1);
#pragma unroll
        for (int kk = 0; kk < 2; ++kk)
#pragma unroll
            for (int i = 0; i < 4; ++i)
#pragma unroll
                for (int j = 0; j < 2*NJ; ++j)
                    acc[i][j] = mfma16(af[kk][i], bf[kk][j], acc[i][j]);
        __builtin_amdgcn_s_setprio(0);
        __builtin_amdgcn_s_barrier();
        if (it + 2 < nk) stage(it + 2, buf);
    }

#pragma unroll
    for (int i = 0; i < 4; ++i) {
#pragma unroll
        for (int r = 0; r < 4; ++r) {
            int row = bm*128 + wm*64 + i*16 + lh*4 + r;
#pragma unroll
            for (int j = 0; j < 2*NJ; ++j) {
                int col = bn*BN + wn*(32*NJ) + j*16 + lr;
                float v = acc[i][j][r];
                if (EPI == 0) {
                    ((unsigned short*)outp)[(size_t)row*N + col] = f2bf(v);
                } else if (EPI == 1) {
                    v += bias[col];
                    v = gelu_f(v);
                    ((unsigned short*)outp)[(size_t)row*N + col] = f2bf(v);
                } else {
                    if (bias) v += bias[col];
                    v += resid[(size_t)row*N + col];
                    ((float*)outp)[(size_t)row*N + col] = v;
                }
            }
        }
    }
}

// ---- V transpose: qkv v-section [b,s,h,dk] -> vt[bh][dk][s] ----
__global__ __launch_bounds__(256) void vtrans_kernel(
    const unsigned short* __restrict__ qkv, unsigned short* __restrict__ vt)
{
    __shared__ unsigned short tl[64][65];
    int bid = blockIdx.x;
    int sblk = bid & 15, bh = bid >> 4;
    int b = bh / H_, h = bh % H_;
    int t = threadIdx.x, tx = t & 63, ty = t >> 6;
    int s0 = sblk * 64;
#pragma unroll
    for (int j = 0; j < 16; ++j) {
        int s = j*4 + ty;
        tl[s][tx] = qkv[(size_t)(b*S_ + s0 + s)*2304 + 1536 + h*64 + tx];
    }
    __syncthreads();
#pragma unroll
    for (int j = 0; j < 16; ++j) {
        int dk = j*4 + ty;
        vt[((size_t)bh*64 + dk)*S_ + s0 + tx] = tl[tx][dk];
    }
}

// ---- flash attention v3: swapped-operand QK^T (S^T), in-register P ----
__global__ __launch_bounds__(256, 3) void attn_kernel(
    const unsigned short* __restrict__ qkv, const unsigned short* __restrict__ vt,
    unsigned short* __restrict__ out)
{
    __shared__ unsigned short Kl[2][64*64];   // [kv][dk], swizzled
    __shared__ unsigned short Vl[2][64*64];   // [dk][kv], swizzled

    const int p = blockIdx.x;
    const int l = (p & 7) * 96 + (p >> 3);    // XCD swizzle: 768 % 8 == 0
    const int qb = l & 7, bh = l >> 3;
    const int b = bh / H_, h = bh % H_;
    const int t = threadIdx.x, lane = t & 63, w = t >> 6;
    const int lr = lane & 15, lh = lane >> 4;
    const int sz = (lr & 7) << 3;             // XOR swizzle (ushort units)

    const float SC = 0.125f * 1.44269504089f; // DK^-0.5 * log2(e)

    // Q as B-fragments (col = q = lr): bq[qi][c]
    const int qrow0 = qb*128 + w*32;
    short8 bq[2][2];
#pragma unroll
    for (int qi = 0; qi < 2; ++qi) {
        const unsigned short* qp = qkv + (size_t)(b*S_ + qrow0 + qi*16 + lr)*2304 + h*64;
#pragma unroll
        for (int c = 0; c < 2; ++c)
            bq[qi][c] = *reinterpret_cast<const short8*>(&qp[c*32 + lh*8]);
    }

    float m_run[2] = {-1e30f, -1e30f};
    float l_run[2] = {0.f, 0.f};              // per-lane partial (cross-lh deferred)
    f32x4 o[2][4] = {};                       // O^T: row d=j*16+lh*4+r, col q=lr

    const char* kgbase = (const char*)qkv;
    const char* vgbase = (const char*)vt;

    auto stage = [&](int kb, int buf) {
        const int ks = kb * 64;
#pragma unroll
        for (int shot = 0; shot < 2; ++shot) {
            int d = shot*4096 + t*16;          // linear dest byte in 8KB tile
            int row = d >> 7;                  // 128 B per row
            int colb = d & 127;
            int sc = colb ^ ((row & 7) << 4);  // pre-swizzled source (involution)
            const char* ksrc = kgbase + ((size_t)(b*S_ + ks + row)*2304 + 768 + h*64)*2 + sc;
            gload16(ksrc, (char*)&Kl[buf][0] + d);
            const char* vsrc = vgbase + ((size_t)(bh*64 + row)*1024 + ks)*2 + sc;
            gload16(vsrc, (char*)&Vl[buf][0] + d);
        }
    };

    stage(0, 0);
    asm volatile("s_waitcnt vmcnt(0)" ::: "memory");
    __builtin_amdgcn_s_barrier();

    for (int kb = 0; kb < 16; ++kb) {
        const int buf = kb & 1;
        if (kb < 15) stage(kb + 1, buf ^ 1);

        // K as A-fragments (rows = k_local)
        short8 ak[4][2];
#pragma unroll
        for (int j = 0; j < 4; ++j)
#pragma unroll
            for (int c = 0; c < 2; ++c)
                ak[j][c] = *reinterpret_cast<const short8*>(
                    &Kl[buf][(j*16 + lr)*64 + ((c*32 + lh*8) ^ sz)]);

        // V as A-fragments with pi permutation: av[j][ks], two b64 reads each
        short8 av[4][2];
#pragma unroll
        for (int j = 0; j < 4; ++j) {
            const unsigned short* vrow = &Vl[buf][(j*16 + lr)*64];
#pragma unroll
            for (int ks = 0; ks < 2; ++ks) {
                short4v lo = *reinterpret_cast<const short4v*>(&vrow[(ks*32 + lh*4)      ^ sz]);
                short4v hi = *reinterpret_cast<const short4v*>(&vrow[(ks*32 + 16 + lh*4) ^ sz]);
                av[j][ks] = __builtin_shufflevector(lo, hi, 0,1,2,3,4,5,6,7);
            }
        }

#pragma unroll
        for (int qi = 0; qi < 2; ++qi) {
            // S^T = K·Q: row = k_local = j*16+lh*4+r, col = q = lr (raw, unscaled)
            f32x4 s[4];
            __builtin_amdgcn_s_setprio(1);
#pragma unroll
            for (int j = 0; j < 4; ++j) {
                f32x4 z = {0.f, 0.f, 0.f, 0.f};
                z = mfma16(ak[j][0], bq[qi][0], z);
                z = mfma16(ak[j][1], bq[qi][1], z);
                s[j] = z;
            }
            __builtin_amdgcn_s_setprio(0);

            // in-lane max over 16 raw values, scale once, 2 cross-lh shuffles
            float m01 = fmaxf(fmaxf(s[0][0], s[0][1]), fmaxf(s[0][2], s[0][3]));
            float m1  = fmaxf(fmaxf(s[1][0], s[1][1]), fmaxf(s[1][2], s[1][3]));
            float m2  = fmaxf(fmaxf(s[2][0], s[2][1]), fmaxf(s[2][2], s[2][3]));
            float m3  = fmaxf(fmaxf(s[3][0], s[3][1]), fmaxf(s[3][2], s[3][3]));
            float mt = fmaxf(fmaxf(m01, m1), fmaxf(m2, m3)) * SC;
            mt = fmaxf(mt, __shfl_xor(mt, 16));
            mt = fmaxf(mt, __shfl_xor(mt, 32));

            // defer-max (T13, THR=8 in log2 domain)
            if (__any(mt > m_run[qi] + 8.0f)) {
                float mn = fmaxf(m_run[qi], mt);
                float a  = exp2f(m_run[qi] - mn);
                m_run[qi] = mn;
                l_run[qi] *= a;
#pragma unroll
                for (int j = 0; j < 4; ++j)
#pragma unroll
                    for (int r = 0; r < 4; ++r) o[qi][j][r] *= a;
            }

            // P = 2^(s*SC - m); in-lane partial row sum
            const float negm = -m_run[qi];
            float rs = 0.f;
#pragma unroll
            for (int j = 0; j < 4; ++j)
#pragma unroll
                for (int r = 0; r < 4; ++r) {
                    float pv = exp2f(__builtin_fmaf(s[j][r], SC, negm));
                    s[j][r] = pv;
                    rs += pv;
                }
            l_run[qi] += rs;

            // pack P -> B-fragments (natural layout; pi applied on V side)
            uint4v u0 = { pkbf(s[0][0], s[0][1]), pkbf(s[0][2], s[0][3]),
                          pkbf(s[1][0], s[1][1]), pkbf(s[1][2], s[1][3]) };
            uint4v u1 = { pkbf(s[2][0], s[2][1]), pkbf(s[2][2], s[2][3]),
                          pkbf(s[3][0], s[3][1]), pkbf(s[3][2], s[3][3]) };
            short8 pb0 = __builtin_bit_cast(short8, u0);
            short8 pb1 = __builtin_bit_cast(short8, u1);

            __builtin_amdgcn_s_setprio(1);
#pragma unroll
            for (int j = 0; j < 4; ++j) {
                o[qi][j] = mfma16(av[j][0], pb0, o[qi][j]);
                o[qi][j] = mfma16(av[j][1], pb1, o[qi][j]);
            }
            __builtin_amdgcn_s_setprio(0);
        }

        asm volatile("s_waitcnt vmcnt(0)" ::: "memory");
        __builtin_amdgcn_s_barrier();
    }

    // epilogue: finish l reduction across lh, normalize, vectorized 8B stores
#pragma unroll
    for (int qi = 0; qi < 2; ++qi) {
        float ls = l_run[qi];
        ls += __shfl_xor(ls, 16);
        ls += __shfl_xor(ls, 32);
        float inv = 1.0f / ls;
        int q = qrow0 + qi*16 + lr;
        unsigned short* orow = out + (size_t)(b*S_ + q)*D_ + h*64;
#pragma unroll
        for (int j = 0; j < 4; ++j) {
            uint2v vv = { pkbf(o[qi][j][0]*inv, o[qi][j][1]*inv),
                          pkbf(o[qi][j][2]*inv, o[qi][j][3]*inv) };
            *reinterpret_cast<uint2v*>(&orow[j*16 + lh*4]) = vv;
        }
    }
}

extern "C" void kernel_launch(void* const* d_in, const int* in_sizes, int n_in,
                              void* d_out, int out_size, void* d_ws, size_t ws_size,
                              hipStream_t stream)
{
    (void)in_sizes; (void)n_in; (void)out_size; (void)ws_size;
    const float* x   = (const float*)d_in[0];
    const float* Wq  = (const float*)d_in[1];
    const float* Wk  = (const float*)d_in[2];
    const float* Wv  = (const float*)d_in[3];
    const float* Wo  = (const float*)d_in[4];
    const float* g1  = (const float*)d_in[5];
    const float* b1  = (const float*)d_in[6];
    const float* g2  = (const float*)d_in[7];
    const float* b2  = (const float*)d_in[8];
    const float* W1  = (const float*)d_in[9];
    const float* bW1 = (const float*)d_in[10];
    const float* W2  = (const float*)d_in[11];
    const float* bW2 = (const float*)d_in[12];
    float* out = (float*)d_out;

    char* ws = (char*)d_ws;
    unsigned short* wt_qkv = (unsigned short*)(ws);            // [2304][768] + wt_o after
    unsigned short* wt_o   = (unsigned short*)(ws + 3538944);  // [768][768]
    unsigned short* wt_1   = (unsigned short*)(ws + 4718592);  // [3072][768]
    unsigned short* wt_2   = (unsigned short*)(ws + 9437184);  // [768][3072]
    unsigned short* slotA  = (unsigned short*)(ws + 14155776); // [8192][768] bf16
    unsigned short* qkv    = (unsigned short*)(ws + 26738688); // [8192][2304] bf16
    unsigned short* vt     = (unsigned short*)(ws + 64487424); // [96][64][1024] bf16
    unsigned short* ffm    = qkv;                              // [8192][3072] bf16 (reuse)

    dim3 tb(32, 8);
    wtrans4_kernel<<<dim3(24,24,4), tb, 0, stream>>>(Wq, Wk, Wv, Wo, wt_qkv);
    wtrans_kernel<<<dim3(96,24), tb, 0, stream>>>(W1, wt_1, 768, 3072);
    wtrans_kernel<<<dim3(24,96), tb, 0, stream>>>(W2, wt_2, 3072, 768);

    ln_kernel<<<M_, 256, 0, stream>>>(x, g1, b1, slotA);
    gemm_kernel<128,0><<<64*18, 256, 0, stream>>>(slotA, wt_qkv, nullptr, nullptr, qkv, 2304, 768);
    vtrans_kernel<<<1536, 256, 0, stream>>>(qkv, vt);
    attn_kernel<<<768, 256, 0, stream>>>(qkv, vt, slotA);
    gemm_kernel<64,2><<<64*12, 256, 0, stream>>>(slotA, wt_o, nullptr, x, (void*)out, 768, 768);
    ln_kernel<<<M_, 256, 0, stream>>>(out, g2, b2, slotA);
    gemm_kernel<128,1><<<64*24, 256, 0, stream>>>(slotA, wt_1, bW1, nullptr, ffm, 3072, 768);
    gemm_kernel<64,2><<<64*12, 256, 0, stream>>>(ffm, wt_2, bW2, out, (void*)out, 768, 3072);
}